// Round 2
// baseline (680.361 us; speedup 1.0000x reference)
//
#include <hip/hip_runtime.h>
#include <hip/hip_bf16.h>
#include <stdint.h>

// ---------------------------------------------------------------------------
// Bahdanau additive attention, B=32, T=2048, D=U=1024. fp32 in/out.
//   q_proj = query@W1 + b1              [B,U]
//   score[b,t] = Wv . tanh(q_proj[b,:] + values[b,t,:]@W2 + b2) + bv
//   w = softmax_t(score); ctx[b,:] = sum_t w[b,t] * values[b,t,:]
// Outputs (fp32, flat): ctx [32*1024] then weights [32*2048].
// GEMM runs in bf16 MFMA (values/W2 converted on the fly), fp32 accumulate.
// ---------------------------------------------------------------------------

typedef unsigned short ushort_t;
typedef short bf16x8 __attribute__((ext_vector_type(8)));
typedef float f32x4 __attribute__((ext_vector_type(4)));

#define GLOBAL_AS __attribute__((address_space(1)))
#define LDS_AS    __attribute__((address_space(3)))

__device__ __forceinline__ ushort_t f2bf(float f) {
    union { float f; unsigned int u; } v;
    v.f = f;
    unsigned int u = v.u;
    unsigned int r = u + 0x7FFFu + ((u >> 16) & 1u);  // RNE
    return (ushort_t)(r >> 16);
}
// pack 2 fp32 -> 2 bf16 in one uint (v_cvt_pk_bf16_f32 on gfx950)
__device__ __forceinline__ unsigned int pk2(float a, float b) {
    union { __hip_bfloat162 h; unsigned int u; } c;
    c.h = __float22bfloat162_rn(make_float2(a, b));
    return c.u;
}

static constexpr int B_ = 32, T_ = 2048, D_ = 1024, U_ = 1024;
static constexpr int M_ = B_ * T_;  // 65536

// ---------------- kernel 1: W2 [D][U] fp32 -> W2T [U][D] bf16 --------------
__global__ __launch_bounds__(256) void k_transpose_w2(const float* __restrict__ W2,
                                                      ushort_t* __restrict__ W2T) {
    __shared__ float tile[32][33];
    int u0 = blockIdx.x * 32, d0 = blockIdx.y * 32;
    int tx = threadIdx.x & 31, ty = threadIdx.x >> 5;  // 32 x 8
#pragma unroll
    for (int r = 0; r < 4; ++r) {
        int dd = ty + r * 8;
        tile[dd][tx] = W2[(size_t)(d0 + dd) * U_ + (u0 + tx)];
    }
    __syncthreads();
#pragma unroll
    for (int r = 0; r < 4; ++r) {
        int uu = ty + r * 8;
        W2T[(size_t)(u0 + uu) * D_ + (d0 + tx)] = f2bf(tile[tx][uu]);
    }
}

// ---------------- kernel 2: qpb[b][u] = query@W1 + b1 + b2 (fp32) ----------
__global__ __launch_bounds__(256) void k_qproj(const float* __restrict__ query,
                                               const float* __restrict__ W1,
                                               const float* __restrict__ b1,
                                               const float* __restrict__ b2,
                                               float* __restrict__ qpb) {
    int b = blockIdx.y;
    int u = blockIdx.x * 256 + threadIdx.x;
    __shared__ float qs[D_];
    for (int i = threadIdx.x; i < D_; i += 256) qs[i] = query[b * D_ + i];
    __syncthreads();
    float acc = 0.f;
    for (int d = 0; d < D_; ++d) acc += qs[d] * W1[(size_t)d * U_ + u];
    qpb[b * U_ + u] = acc + b1[u] + b2[u];
}

// ---------------- kernel 3: fused GEMM + tanh + Wv-dot ---------------------
// C = values[M,K] x W2T[N,K]^T ; per 128x128 tile emit per-row partial score.
#define BM 128
#define BN 128
#define BK 64

__global__ __launch_bounds__(256) void k_score_gemm(const float* __restrict__ values,
                                                    const ushort_t* __restrict__ W2T,
                                                    const float* __restrict__ qpb,
                                                    const float* __restrict__ Wv,
                                                    float* __restrict__ scores_partial) {
    __shared__ ushort_t As[BM * BK];  // [m][k] bf16, 16 KB
    __shared__ ushort_t Bs[BN * BK];  // [n][k] bf16, 16 KB (global_load_lds layout)
    __shared__ float sScore[BM];

    const int tid = threadIdx.x;
    const int lane = tid & 63;
    const int w = tid >> 6;       // wave 0..3
    const int wm = w >> 1;        // 0..1
    const int wn = w & 1;         // 0..1
    const int n0 = blockIdx.x * BN;
    const int m0 = blockIdx.y * BM;

    if (tid < BM) sScore[tid] = 0.f;

    f32x4 acc[4][4];
#pragma unroll
    for (int i = 0; i < 4; ++i)
#pragma unroll
        for (int j = 0; j < 4; ++j) acc[i][j] = (f32x4){0.f, 0.f, 0.f, 0.f};

    // A staging: fp32 -> bf16 inline. thread covers rows i*16+rr, cols cc*4..+3
    const int rr = tid >> 4;   // 0..15
    const int cc = tid & 15;   // 0..15
    const float* aSrc = values + (size_t)(m0 + rr) * D_ + cc * 4;
    ushort_t* aDst = As + rr * BK + cc * 4;

    // B staging via global_load_lds: lane covers row w*8+(lane>>3), cols (lane&7)*8
    const int mB = lane >> 3;
    const int kB = (lane & 7) * 8;
    const ushort_t* bBase = W2T + (size_t)(n0 + w * 8 + mB) * D_ + kB;

    const int quad = lane >> 4;
    const int l15 = lane & 15;

    for (int k0 = 0; k0 < D_; k0 += BK) {
        // B first: DMA overlaps the A-side VALU conversion
#pragma unroll
        for (int i = 0; i < 4; ++i) {
            __builtin_amdgcn_global_load_lds(
                (const GLOBAL_AS void*)(bBase + k0 + (size_t)i * 32 * D_),
                (LDS_AS void*)(Bs + i * 2048 + w * 512), 16, 0, 0);
        }
#pragma unroll
        for (int i = 0; i < 8; ++i) {
            f32x4 v = *(const f32x4*)(aSrc + k0 + (size_t)i * 16 * D_);
            uint2 p;
            p.x = pk2(v[0], v[1]);
            p.y = pk2(v[2], v[3]);
            *(uint2*)(aDst + i * 16 * BK) = p;
        }
        __syncthreads();
#pragma unroll
        for (int kk = 0; kk < BK; kk += 32) {
            bf16x8 af[4], bfr[4];
            const int col = kk + quad * 8;
#pragma unroll
            for (int i = 0; i < 4; ++i)
                af[i] = *(const bf16x8*)(As + (wm * 64 + i * 16 + l15) * BK + col);
#pragma unroll
            for (int j = 0; j < 4; ++j)
                bfr[j] = *(const bf16x8*)(Bs + (wn * 64 + j * 16 + l15) * BK + col);
#pragma unroll
            for (int i = 0; i < 4; ++i)
#pragma unroll
                for (int j = 0; j < 4; ++j)
                    acc[i][j] = __builtin_amdgcn_mfma_f32_16x16x32_bf16(
                        af[i], bfr[j], acc[i][j], 0, 0, 0);
        }
        __syncthreads();
    }

    // epilogue: score contribution = sum_n tanh(acc + qpb[b][u]) * Wv[u]
    // C layout: row = wm*64 + i*16 + quad*4 + r, col(u) = n0 + wn*64 + j*16 + l15
    const int b = m0 >> 11;  // 2048 rows per batch; BM=128 never crosses b
    const float* qp = qpb + b * U_;
    float qv[4], wv[4];
#pragma unroll
    for (int j = 0; j < 4; ++j) {
        int u = n0 + wn * 64 + j * 16 + l15;
        qv[j] = qp[u];
        wv[j] = Wv[u];
    }
#pragma unroll
    for (int i = 0; i < 4; ++i) {
#pragma unroll
        for (int r = 0; r < 4; ++r) {
            float s = 0.f;
#pragma unroll
            for (int j = 0; j < 4; ++j) s += tanhf(acc[i][j][r] + qv[j]) * wv[j];
            // reduce the 16 lanes of this quad (they hold cols l15=0..15)
            s += __shfl_xor(s, 1);
            s += __shfl_xor(s, 2);
            s += __shfl_xor(s, 4);
            s += __shfl_xor(s, 8);
            if (l15 == 0) atomicAdd(&sScore[wm * 64 + i * 16 + quad * 4 + r], s);
        }
    }
    __syncthreads();
    if (tid < BM) scores_partial[(size_t)(m0 + tid) * 8 + blockIdx.x] = sScore[tid];
}

// ---------------- kernel 4: softmax over T per batch -----------------------
__global__ __launch_bounds__(256) void k_softmax(const float* __restrict__ scores_partial,
                                                 const float* __restrict__ bv,
                                                 float* __restrict__ w_f,
                                                 float* __restrict__ out_w) {
    const int b = blockIdx.x;
    __shared__ float s[T_];
    __shared__ float red[4];
    const int tid = threadIdx.x;
    const float bvf = bv[0];

    float lmax = -1e30f;
    for (int t = tid; t < T_; t += 256) {
        const float* p = scores_partial + (size_t)(b * T_ + t) * 8;
        float sc = ((p[0] + p[1]) + (p[2] + p[3])) + ((p[4] + p[5]) + (p[6] + p[7])) + bvf;
        s[t] = sc;
        lmax = fmaxf(lmax, sc);
    }
    for (int off = 32; off; off >>= 1) lmax = fmaxf(lmax, __shfl_xor(lmax, off));
    if ((tid & 63) == 0) red[tid >> 6] = lmax;
    __syncthreads();
    const float gmax = fmaxf(fmaxf(red[0], red[1]), fmaxf(red[2], red[3]));

    float lsum = 0.f;
    for (int t = tid; t < T_; t += 256) {
        float e = expf(s[t] - gmax);
        s[t] = e;
        lsum += e;
    }
    for (int off = 32; off; off >>= 1) lsum += __shfl_xor(lsum, off);
    __syncthreads();
    if ((tid & 63) == 0) red[tid >> 6] = lsum;
    __syncthreads();
    const float ginv = 1.f / ((red[0] + red[1]) + (red[2] + red[3]));

    for (int t = tid; t < T_; t += 256) {
        float wgt = s[t] * ginv;
        w_f[b * T_ + t] = wgt;
        out_w[b * T_ + t] = wgt;
    }
}

// ---------------- kernel 5: ctx partials over 256-row T chunks -------------
__global__ __launch_bounds__(256) void k_ctx_partial(const float* __restrict__ values,
                                                     const float* __restrict__ w_f,
                                                     float* __restrict__ ctx_partial) {
    const int tc = blockIdx.x;  // 0..7
    const int b = blockIdx.y;   // 0..31
    const int tid = threadIdx.x;

    f32x4 acc = (f32x4){0.f, 0.f, 0.f, 0.f};
    const float* base = values + (size_t)(b * T_ + tc * 256) * D_ + tid * 4;
    const float* wrow = w_f + b * T_ + tc * 256;
    for (int tt = 0; tt < 256; ++tt) {
        const float wgt = wrow[tt];
        f32x4 v = *(const f32x4*)(base + (size_t)tt * D_);
        acc += wgt * v;
    }
    *(f32x4*)(ctx_partial + (size_t)(b * 8 + tc) * D_ + tid * 4) = acc;
}

// ---------------- kernel 6: reduce 8 partials --------------------------------
__global__ __launch_bounds__(256) void k_ctx_reduce(const float* __restrict__ ctx_partial,
                                                    float* __restrict__ out_ctx) {
    const int b = blockIdx.x;
    const int d = blockIdx.y * 256 + threadIdx.x;
    float s = 0.f;
#pragma unroll
    for (int p = 0; p < 8; ++p) s += ctx_partial[(size_t)(b * 8 + p) * D_ + d];
    out_ctx[b * D_ + d] = s;
}

// ---------------------------------------------------------------------------
extern "C" void kernel_launch(void* const* d_in, const int* in_sizes, int n_in,
                              void* d_out, int out_size, void* d_ws, size_t ws_size,
                              hipStream_t stream) {
    const float* query  = (const float*)d_in[0];
    const float* values = (const float*)d_in[1];
    const float* W1     = (const float*)d_in[2];
    const float* b1     = (const float*)d_in[3];
    const float* W2     = (const float*)d_in[4];
    const float* b2     = (const float*)d_in[5];
    const float* Wv     = (const float*)d_in[6];
    const float* bv     = (const float*)d_in[7];

    float* out_ctx = (float*)d_out;          // [32*1024]
    float* out_w   = out_ctx + B_ * D_;      // [32*2048]

    // workspace layout (bytes), ~5.5 MB, fully rewritten every launch
    char* ws = (char*)d_ws;
    ushort_t* W2T            = (ushort_t*)(ws);                        // 2 MB
    float*    qpb            = (float*)(ws + (2u << 20));              // 128 KB
    float*    scores_partial = (float*)(ws + (2u << 20) + 131072);     // 2 MB
    float*    w_f            = (float*)(ws + (4u << 20) + 131072);     // 256 KB
    float*    ctx_partial    = (float*)(ws + (4u << 20) + 131072 + 262144);  // 1 MB

    k_transpose_w2<<<dim3(U_ / 32, D_ / 32), 256, 0, stream>>>(W2, W2T);
    k_qproj<<<dim3(U_ / 256, B_), 256, 0, stream>>>(query, W1, b1, b2, qpb);
    k_score_gemm<<<dim3(U_ / BN, M_ / BM), 256, 0, stream>>>(values, W2T, qpb, Wv,
                                                             scores_partial);
    k_softmax<<<dim3(B_), 256, 0, stream>>>(scores_partial, bv, w_f, out_w);
    k_ctx_partial<<<dim3(8, B_), 256, 0, stream>>>(values, w_f, ctx_partial);
    k_ctx_reduce<<<dim3(B_, D_ / 256), 256, 0, stream>>>(ctx_partial, out_ctx);

    (void)in_sizes; (void)n_in; (void)out_size; (void)ws_size;
}